// Round 2
// baseline (450.395 us; speedup 1.0000x reference)
//
#include <hip/hip_runtime.h>
#include <hip/hip_bf16.h>
#include <cstdint>

#define Bsz 32
#define Dd 2048
#define Ff 512

typedef __attribute__((ext_vector_type(8))) short short8;
typedef __attribute__((ext_vector_type(4))) float floatx4;

__device__ inline unsigned short f2bf(float f) {
  union { float f; unsigned int u; } c; c.f = f;
  unsigned int u = c.u;
  return (unsigned short)((u + 0x7FFFu + ((u >> 16) & 1u)) >> 16);
}

__device__ inline void gld_lds16(const void* g, void* l) {
  __builtin_amdgcn_global_load_lds(
      (const __attribute__((address_space(1))) void*)g,
      (__attribute__((address_space(3))) void*)l,
      16, 0, 0);
}

// K1: abs_sum[j] = sum_k |s[j] - s[k]|. 8 blocks, no atomics.
__global__ __launch_bounds__(256) void k_prep(const float* __restrict__ s,
                                              float* __restrict__ abs_sum) {
  __shared__ float sk[256];
  int t = threadIdx.x;
  int j = blockIdx.x * 256 + t;
  float sj = s[j];
  float acc = 0.f;
  for (int c = 0; c < Dd; c += 256) {
    __syncthreads();
    sk[t] = s[c + t];
    __syncthreads();
#pragma unroll 16
    for (int k = 0; k < 256; ++k) acc += fabsf(sj - sk[k]);
  }
  abs_sum[j] = acc;
}

// K2: per P-row i: m_i = max_j(scal_i*s_j - abs_sum_j), inv_i = 1/sum_j exp(.-m_i).
// One wave per row, 4 rows/block.
__global__ __launch_bounds__(256) void k_rowstats(const float* __restrict__ s,
                                                  const float* __restrict__ abs_sum,
                                                  float* __restrict__ mrow,
                                                  float* __restrict__ inv) {
  int w = threadIdx.x >> 6, l = threadIdx.x & 63;
  int i = blockIdx.x * 4 + w;
  float scal = 2047.0f - 2.0f * (float)i;  // D+1-2*(i+1)
  float v[32];
  float vmax = -3.4e38f;
#pragma unroll
  for (int it = 0; it < 32; ++it) {
    int j = it * 64 + l;
    v[it] = fmaf(scal, s[j], -abs_sum[j]);
    vmax = fmaxf(vmax, v[it]);
  }
#pragma unroll
  for (int off = 32; off > 0; off >>= 1) vmax = fmaxf(vmax, __shfl_xor(vmax, off, 64));
  float sum = 0.f;
#pragma unroll
  for (int it = 0; it < 32; ++it) sum += __expf(v[it] - vmax);
#pragma unroll
  for (int off = 32; off > 0; off >>= 1) sum += __shfl_xor(sum, off, 64);
  if (l == 0) { mrow[i] = vmax; inv[i] = 1.0f / sum; }
}

// K3: PT[j][d] = P[d][j] = exp(scal_d*s_j - abs_sum_j - m_d) * inv_d, bf16,
// written coalesced (d contiguous, 2 per uint store).
__global__ __launch_bounds__(256) void k_pt(const float* __restrict__ s,
                                            const float* __restrict__ abs_sum,
                                            const float* __restrict__ mrow,
                                            const float* __restrict__ inv,
                                            unsigned int* __restrict__ PTw) {
  int j = blockIdx.y;
  int d0 = (blockIdx.x * 256 + threadIdx.x) * 2;
  float sj = s[j], asj = abs_sum[j];
  float m0v = mrow[d0], m1v = mrow[d0 + 1];
  float i0v = inv[d0], i1v = inv[d0 + 1];
  float scal0 = 2047.0f - 2.0f * (float)d0;
  float scal1 = scal0 - 2.0f;
  float p0 = __expf(fmaf(scal0, sj, -asj) - m0v) * i0v;
  float p1 = __expf(fmaf(scal1, sj, -asj) - m1v) * i1v;
  unsigned int v = (unsigned int)f2bf(p0) | ((unsigned int)f2bf(p1) << 16);
  PTw[((size_t)j * Dd + d0) >> 1] = v;
}

// K4: XT[b][f][d] = bf16(x[b][d][f]), 64x64 LDS tiles, packed 4B stores.
__global__ __launch_bounds__(256) void k_xt(const float* __restrict__ x,
                                            unsigned short* __restrict__ XT) {
  __shared__ unsigned short tile[64][65];
  int t = threadIdx.x;
  int tx = t & 63, ty = t >> 6;
  int d0 = blockIdx.x * 64, f0 = blockIdx.y * 64;
  const float* xb = x + (size_t)blockIdx.z * Dd * Ff;
#pragma unroll
  for (int r = ty; r < 64; r += 4)
    tile[r][tx] = f2bf(xb[(size_t)(d0 + r) * Ff + f0 + tx]);
  __syncthreads();
  unsigned int* xtw = (unsigned int*)(XT + (size_t)blockIdx.z * Ff * Dd);
  int dh = t & 31, fy = t >> 5;
#pragma unroll
  for (int fr = fy; fr < 64; fr += 8) {
    unsigned int v = (unsigned int)tile[2 * dh][fr] | ((unsigned int)tile[2 * dh + 1][fr] << 16);
    xtw[((size_t)(f0 + fr) * Dd + d0) / 2 + dh] = v;
  }
}

// K5: batched GEMM. C[b][m][n] = sum_k PT[m][k] * XT[b][n][k].
// 128x128 tile, BK=64 (32 barriers, 32 MFMA/wave/barrier), gld_lds w=16.
#define BM 128
#define BN 128
#define BK 64

__global__ __launch_bounds__(256) void k_gemm(const unsigned short* __restrict__ PT,
                                              const unsigned short* __restrict__ XT,
                                              float* __restrict__ out) {
  __shared__ unsigned short As[BM * BK];  // 16 KB, rows of 128B
  __shared__ unsigned short Bs[BN * BK];  // 16 KB
  int t = threadIdx.x;

  // swizzle: 128 consecutive blocks share one PT slab (512 KB -> L2-hot)
  int id = blockIdx.x;
  int mt = id >> 7;          // 0..15
  int rem = id & 127;
  int bz = rem >> 2;         // 0..31
  int nt = rem & 3;          // 0..3
  int m0 = mt * BM;
  int n0 = nt * BN;
  const unsigned short* Bsrc = XT + (size_t)bz * Ff * Dd;
  float* Cb = out + (size_t)bz * Dd * Ff;

  int l = t & 63, w = t >> 6;
  int wm = (w & 1) * 64, wn = (w >> 1) * 64;
  int lm = l & 15, lq = l >> 4;

  floatx4 acc[4][4];
#pragma unroll
  for (int i = 0; i < 4; ++i)
#pragma unroll
    for (int j = 0; j < 4; ++j) acc[i][j] = {0.f, 0.f, 0.f, 0.f};

  for (int k0 = 0; k0 < Dd; k0 += BK) {
    __syncthreads();
#pragma unroll
    for (int q = 0; q < 4; ++q) {
      int c = t + q * 256;
      int row = c >> 3, kk = (c & 7) * 8;
      gld_lds16(PT + (size_t)(m0 + row) * Dd + k0 + kk, &As[c * 8]);
      gld_lds16(Bsrc + (size_t)(n0 + row) * Dd + k0 + kk, &Bs[c * 8]);
    }
    __syncthreads();

#pragma unroll
    for (int h = 0; h < 2; ++h) {
      short8 a[4], b[4];
#pragma unroll
      for (int mi = 0; mi < 4; ++mi)
        a[mi] = *(const short8*)&As[(wm + mi * 16 + lm) * BK + h * 32 + lq * 8];
#pragma unroll
      for (int ni = 0; ni < 4; ++ni)
        b[ni] = *(const short8*)&Bs[(wn + ni * 16 + lm) * BK + h * 32 + lq * 8];
#pragma unroll
      for (int mi = 0; mi < 4; ++mi)
#pragma unroll
        for (int ni = 0; ni < 4; ++ni)
          acc[mi][ni] = __builtin_amdgcn_mfma_f32_16x16x32_bf16(a[mi], b[ni], acc[mi][ni], 0, 0, 0);
    }
  }

  // epilogue: C/D layout col=lane&15, row=(lane>>4)*4+reg (m89-verified)
#pragma unroll
  for (int mi = 0; mi < 4; ++mi) {
#pragma unroll
    for (int r = 0; r < 4; ++r) {
      int row = m0 + wm + mi * 16 + lq * 4 + r;
#pragma unroll
      for (int ni = 0; ni < 4; ++ni) {
        int col = n0 + wn + ni * 16 + lm;
        Cb[(size_t)row * Ff + col] = acc[mi][ni][r];
      }
    }
  }
}

extern "C" void kernel_launch(void* const* d_in, const int* in_sizes, int n_in,
                              void* d_out, int out_size, void* d_ws, size_t ws_size,
                              hipStream_t stream) {
  const float* x = (const float*)d_in[0];
  const float* s = (const float*)d_in[1];
  float* out = (float*)d_out;

  char* ws = (char*)d_ws;
  float* abs_sum = (float*)ws;                                   // 8 KB
  float* mrow = (float*)(ws + 8192);                             // 8 KB
  float* inv = (float*)(ws + 16384);                             // 8 KB
  unsigned short* PT = (unsigned short*)(ws + 24576);            // 8 MB
  unsigned short* XT = (unsigned short*)(ws + 24576 + 8388608);  // 64 MB

  k_prep<<<Dd / 256, 256, 0, stream>>>(s, abs_sum);
  k_rowstats<<<Dd / 4, 256, 0, stream>>>(s, abs_sum, mrow, inv);
  k_pt<<<dim3(Dd / 512, Dd), 256, 0, stream>>>(s, abs_sum, mrow, inv, (unsigned int*)PT);
  k_xt<<<dim3(Dd / 64, Ff / 64, Bsz), 256, 0, stream>>>(x, XT);
  k_gemm<<<(Dd / BM) * (Ff / BN) * Bsz, 256, 0, stream>>>(PT, XT, out);
}

// Round 3
// 404.279 us; speedup vs baseline: 1.1141x; 1.1141x over previous
//
#include <hip/hip_runtime.h>
#include <hip/hip_bf16.h>
#include <cstdint>

#define Bsz 32
#define Dd 2048
#define Ff 512

typedef __attribute__((ext_vector_type(8))) short short8;
typedef __attribute__((ext_vector_type(4))) float floatx4;

__device__ inline unsigned short f2bf(float f) {
  union { float f; unsigned int u; } c; c.f = f;
  unsigned int u = c.u;
  return (unsigned short)((u + 0x7FFFu + ((u >> 16) & 1u)) >> 16);
}

__device__ inline void gld_lds16(const void* g, void* l) {
  __builtin_amdgcn_global_load_lds(
      (const __attribute__((address_space(1))) void*)g,
      (__attribute__((address_space(3))) void*)l,
      16, 0, 0);
}

// K1: abs_sum[j] = sum_k |s[j] - s[k]|.
__global__ __launch_bounds__(256) void k_prep(const float* __restrict__ s,
                                              float* __restrict__ abs_sum) {
  __shared__ float sk[256];
  int t = threadIdx.x;
  int j = blockIdx.x * 256 + t;
  float sj = s[j];
  float acc = 0.f;
  for (int c = 0; c < Dd; c += 256) {
    __syncthreads();
    sk[t] = s[c + t];
    __syncthreads();
#pragma unroll 16
    for (int k = 0; k < 256; ++k) acc += fabsf(sj - sk[k]);
  }
  abs_sum[j] = acc;
}

// K2: per P-row i: m_i, inv_i = softmax stats. One wave per row.
__global__ __launch_bounds__(256) void k_rowstats(const float* __restrict__ s,
                                                  const float* __restrict__ abs_sum,
                                                  float* __restrict__ mrow,
                                                  float* __restrict__ inv) {
  int w = threadIdx.x >> 6, l = threadIdx.x & 63;
  int i = blockIdx.x * 4 + w;
  float scal = 2047.0f - 2.0f * (float)i;  // D+1-2*(i+1)
  float v[32];
  float vmax = -3.4e38f;
#pragma unroll
  for (int it = 0; it < 32; ++it) {
    int j = it * 64 + l;
    v[it] = fmaf(scal, s[j], -abs_sum[j]);
    vmax = fmaxf(vmax, v[it]);
  }
#pragma unroll
  for (int off = 32; off > 0; off >>= 1) vmax = fmaxf(vmax, __shfl_xor(vmax, off, 64));
  float sum = 0.f;
#pragma unroll
  for (int it = 0; it < 32; ++it) sum += __expf(v[it] - vmax);
#pragma unroll
  for (int off = 32; off > 0; off >>= 1) sum += __shfl_xor(sum, off, 64);
  if (l == 0) { mrow[i] = vmax; inv[i] = 1.0f / sum; }
}

// K3: PT[j][d] = exp(scal_d*s_j - abs_sum_j - m_d) * inv_d (bf16), uint2 stores.
__global__ __launch_bounds__(256) void k_pt(const float* __restrict__ s,
                                            const float* __restrict__ abs_sum,
                                            const float* __restrict__ mrow,
                                            const float* __restrict__ inv,
                                            uint2* __restrict__ PTw) {
  int j = blockIdx.y;
  int d0 = (blockIdx.x * 256 + threadIdx.x) * 4;
  float sj = s[j], asj = abs_sum[j];
  float4 mv = *(const float4*)&mrow[d0];
  float4 iv = *(const float4*)&inv[d0];
  float sc0 = 2047.0f - 2.0f * (float)d0;
  float base = fmaf(sc0, sj, -asj);
  float step = -2.0f * sj;
  float p0 = __expf(base - mv.x) * iv.x;
  float p1 = __expf(base + step - mv.y) * iv.y;
  float p2 = __expf(base + 2.f * step - mv.z) * iv.z;
  float p3 = __expf(base + 3.f * step - mv.w) * iv.w;
  uint2 v;
  v.x = (unsigned int)f2bf(p0) | ((unsigned int)f2bf(p1) << 16);
  v.y = (unsigned int)f2bf(p2) | ((unsigned int)f2bf(p3) << 16);
  PTw[((size_t)j * Dd + d0) >> 2] = v;
}

// K4: XT[b][f][d] = bf16(x[b][d][f]). 64d x 128f tiles, float2 reads, uint2 stores.
__global__ __launch_bounds__(256) void k_xt(const float* __restrict__ x,
                                            unsigned int* __restrict__ XT) {
  __shared__ unsigned short tile[64][130];  // stride 260 B -> 2-way (free) col reads
  int t = threadIdx.x;
  int d0 = blockIdx.x * 64, f0 = blockIdx.y * 128;
  const float* xb = x + (size_t)blockIdx.z * Dd * Ff;
  int fx = (t & 63) * 2, dy = t >> 6;
#pragma unroll
  for (int r = dy; r < 64; r += 4) {
    float2 v = *(const float2*)&xb[(size_t)(d0 + r) * Ff + f0 + fx];
    tile[r][fx] = f2bf(v.x);
    tile[r][fx + 1] = f2bf(v.y);
  }
  __syncthreads();
  unsigned int* xtw = XT + (size_t)blockIdx.z * Ff * (Dd / 2);
  int dh = t & 15, fy = t >> 4;
#pragma unroll
  for (int fr = fy; fr < 128; fr += 16) {
    uint2 v;
    v.x = (unsigned int)tile[4 * dh][fr] | ((unsigned int)tile[4 * dh + 1][fr] << 16);
    v.y = (unsigned int)tile[4 * dh + 2][fr] | ((unsigned int)tile[4 * dh + 3][fr] << 16);
    *(uint2*)&xtw[(size_t)(f0 + fr) * (Dd / 2) + d0 / 2 + dh * 2] = v;
  }
}

// K5: batched GEMM. C[b][m][n] = sum_k PT[m][k] * XT[b][n][k].
// 128x128 tile, BK=64, gld_lds w=16 with XOR-source-swizzled LDS layout:
// LDS chunk c holds global chunk (row=c>>3, k16=(c&7)^(row&7)) -> fragment
// reads hit 2 lanes/bank (free) instead of 16-way conflicts.
#define BM 128
#define BN 128
#define BK 64

__global__ __launch_bounds__(256) void k_gemm(const unsigned short* __restrict__ PT,
                                              const unsigned short* __restrict__ XT,
                                              float* __restrict__ out) {
  __shared__ unsigned short As[BM * BK];  // 16 KB
  __shared__ unsigned short Bs[BN * BK];  // 16 KB
  int t = threadIdx.x;

  // swizzle: 128 consecutive blocks share one PT slab (512 KB, L2-hot)
  int id = blockIdx.x;
  int mt = id >> 7;
  int rem = id & 127;
  int bz = rem >> 2;
  int nt = rem & 3;
  int m0 = mt * BM;
  int n0 = nt * BN;
  const unsigned short* Bsrc = XT + (size_t)bz * Ff * Dd;
  float* Cb = out + (size_t)bz * Dd * Ff;

  int l = t & 63, w = t >> 6;
  int wm = (w & 1) * 64, wn = (w >> 1) * 64;
  int lm = l & 15, lq = l >> 4;
  int sw = lm & 7;  // row&7 for fragment rows (wm, mi*16 are multiples of 8)

  floatx4 acc[4][4];
#pragma unroll
  for (int i = 0; i < 4; ++i)
#pragma unroll
    for (int j = 0; j < 4; ++j) acc[i][j] = {0.f, 0.f, 0.f, 0.f};

  for (int k0 = 0; k0 < Dd; k0 += BK) {
    __syncthreads();
#pragma unroll
    for (int q = 0; q < 4; ++q) {
      int c = t + q * 256;               // LDS chunk index (16 B each)
      int row = c >> 3;
      int k16 = (c & 7) ^ (row & 7);     // source-swizzled k-chunk
      gld_lds16(PT + (size_t)(m0 + row) * Dd + k0 + k16 * 8, &As[c * 8]);
      gld_lds16(Bsrc + (size_t)(n0 + row) * Dd + k0 + k16 * 8, &Bs[c * 8]);
    }
    __syncthreads();

#pragma unroll
    for (int h = 0; h < 2; ++h) {
      int kc = h * 4 + lq;               // wanted k-chunk
      short8 a[4], b[4];
#pragma unroll
      for (int mi = 0; mi < 4; ++mi) {
        int row = wm + mi * 16 + lm;
        a[mi] = *(const short8*)&As[(row * 8 + (kc ^ sw)) * 8];
      }
#pragma unroll
      for (int ni = 0; ni < 4; ++ni) {
        int row = wn + ni * 16 + lm;
        b[ni] = *(const short8*)&Bs[(row * 8 + (kc ^ sw)) * 8];
      }
#pragma unroll
      for (int mi = 0; mi < 4; ++mi)
#pragma unroll
        for (int ni = 0; ni < 4; ++ni)
          acc[mi][ni] = __builtin_amdgcn_mfma_f32_16x16x32_bf16(a[mi], b[ni], acc[mi][ni], 0, 0, 0);
    }
  }

  // epilogue: C/D layout col=lane&15, row=(lane>>4)*4+reg (m89-verified)
#pragma unroll
  for (int mi = 0; mi < 4; ++mi) {
#pragma unroll
    for (int r = 0; r < 4; ++r) {
      int row = m0 + wm + mi * 16 + lq * 4 + r;
#pragma unroll
      for (int ni = 0; ni < 4; ++ni) {
        int col = n0 + wn + ni * 16 + lm;
        Cb[(size_t)row * Ff + col] = acc[mi][ni][r];
      }
    }
  }
}

extern "C" void kernel_launch(void* const* d_in, const int* in_sizes, int n_in,
                              void* d_out, int out_size, void* d_ws, size_t ws_size,
                              hipStream_t stream) {
  const float* x = (const float*)d_in[0];
  const float* s = (const float*)d_in[1];
  float* out = (float*)d_out;

  char* ws = (char*)d_ws;
  float* abs_sum = (float*)ws;                                   // 8 KB
  float* mrow = (float*)(ws + 8192);                             // 8 KB
  float* inv = (float*)(ws + 16384);                             // 8 KB
  unsigned short* PT = (unsigned short*)(ws + 24576);            // 8 MB
  unsigned short* XT = (unsigned short*)(ws + 24576 + 8388608);  // 64 MB

  k_prep<<<Dd / 256, 256, 0, stream>>>(s, abs_sum);
  k_rowstats<<<Dd / 4, 256, 0, stream>>>(s, abs_sum, mrow, inv);
  k_pt<<<dim3(Dd / 1024, Dd), 256, 0, stream>>>(s, abs_sum, mrow, inv, (uint2*)PT);
  k_xt<<<dim3(Dd / 64, Ff / 128, Bsz), 256, 0, stream>>>(x, (unsigned int*)XT);
  k_gemm<<<(Dd / BM) * (Ff / BN) * Bsz, 256, 0, stream>>>(PT, XT, out);
}